// Round 7
// baseline (250.506 us; speedup 1.0000x reference)
//
#include <hip/hip_runtime.h>

// Problem constants
#define BSZ    8192
#define NWRD   4
#define SEQL   16
#define HDIM   128
#define NSEQ   (BSZ * NWRD)    // 32768
#define WGSEQ  32              // sequences per workgroup
#define UPB    80              // slot capacity per length-bin (80*32=2560 >> E=2048)
#define BINCAP (UPB * WGSEQ)   // 2560
#define NUNITS 1040            // >= sum of ceil(cnt_b/32) (= 1024 + <=16)
#define HSTRIDE 136            // ushorts per seq row (272 B = 17*16, 16B-aligned)

typedef float  f32x4  __attribute__((ext_vector_type(4)));
typedef float  f32x16 __attribute__((ext_vector_type(16)));
typedef __bf16 bf16x8 __attribute__((ext_vector_type(8)));

union AccU { f32x16 v; f32x4 q[4]; float f[16]; };
union HPack { unsigned short s[4]; unsigned long long u64; };

__device__ __forceinline__ unsigned short f2bf(float f) {
    unsigned int u = __builtin_bit_cast(unsigned int, f);
    return (unsigned short)((u + 0x7fff + ((u >> 16) & 1)) >> 16);  // RNE
}
__device__ __forceinline__ float sigm(float x) {
    return __builtin_amdgcn_rcpf(1.f + __builtin_amdgcn_exp2f(x * -1.44269504f));
}
__device__ __forceinline__ float tanhx(float x) {
    return 1.f - 2.f * __builtin_amdgcn_rcpf(1.f + __builtin_amdgcn_exp2f(x * 2.88539008f));
}

// ---------------------------------------------------------------------------
// Fused prep (512 blocks)  [identical to passing R5]:
//  blocks 0..127  : P2T[v][g][j] = b_ih[n]+b_hh[n] + emb[v]·W_ih[n], n=g*128+j
//  blocks 128..383: WA = W_hh bf16, A-fragment order (HW-validated R3..R5)
//  blocks 384..511: binned scatter, bin = 16-len, block-aggregated atomics.
// ---------------------------------------------------------------------------
__global__ void prep4(const float* __restrict__ emb, const float* __restrict__ W_ih,
                      const float* __restrict__ b_ih, const float* __restrict__ b_hh,
                      const float* __restrict__ W_hh, const int* __restrict__ lengths,
                      float* __restrict__ P2T, unsigned short* __restrict__ WA,
                      int* __restrict__ perm, int* __restrict__ gh)
{
    __shared__ int lh[16], gbase[16];
    const int blk = blockIdx.x, tid = threadIdx.x;

    if (blk < 128) {
        int idx = blk * 256 + tid;                 // 32768 = v*512 + g*128 + j
        int v = idx >> 9, g = (idx >> 7) & 3, j = idx & 127;
        int n = g * 128 + j;
        float s = b_ih[n] + b_hh[n];
        const float* er = emb  + v * 128;
        const float* wr = W_ih + n * 128;
        for (int e = 0; e < 128; e += 4)
            s += er[e]*wr[e] + er[e+1]*wr[e+1] + er[e+2]*wr[e+2] + er[e+3]*wr[e+3];
        P2T[idx] = s;
    } else if (blk < 384) {
        int idx = (blk - 128) * 256 + tid;         // 65536
        int jj = idx & 7, lane = (idx >> 3) & 63, kc = (idx >> 9) & 7, tt = idx >> 12;
        int wv = tt >> 2, g = tt & 3;
        int n = g * 128 + wv * 32 + (lane & 31);
        int k = kc * 16 + (lane >> 5) * 8 + jj;
        WA[idx] = f2bf(W_hh[n * 128 + k]);
    } else {
        if (tid < 16) lh[tid] = 0;
        __syncthreads();
        int i = (blk - 384) * 256 + tid;           // 32768 sequences
        int b = 16 - lengths[i];                   // descending-length bins
        int rank = atomicAdd(&lh[b], 1);
        __syncthreads();
        if (tid < 16) gbase[tid] = atomicAdd(&gh[tid], lh[tid]);
        __syncthreads();
        perm[b * BINCAP + gbase[b] + rank] = i;
    }
}

// ---------------------------------------------------------------------------
// LSTM, transposed GEMM: gates^T = W_hh(A, regs) x h^T(B, LDS).
// Work-conserving LPT: block u maps to the u-th real group in descending-
// length order via a prefix scan of bin counts (no dummy units).
// Uniform length per group -> no masking; 1 barrier/step (double-buffered h).
// NEW vs R5: P-gather software prefetch (next step's 16 dwordx4 issued under
// current step's MFMA+trans work -> L2 latency off the critical path).
// ---------------------------------------------------------------------------
__global__ __launch_bounds__(256, 2) void lstm5(
    const int* __restrict__ word_ids, const int* __restrict__ perm,
    const int* __restrict__ gh, const float* __restrict__ P2T,
    const unsigned short* __restrict__ WA, float* __restrict__ c_out)
{
    __shared__ __align__(16) unsigned short hbuf[2][WGSEQ * HSTRIDE];  // 2 x 8704 B
    __shared__ int words_s[WGSEQ * 17];
    __shared__ int sid_s[WGSEQ];

    const int tid    = threadIdx.x;
    const int wv     = tid >> 6;
    const int lane   = tid & 63;
    const int lane31 = lane & 31;
    const int hl     = lane >> 5;

    // map blockIdx -> (bin b, group grp) work-conservingly
    const int u = blockIdx.x;
    int b = -1, grp = 0, cnt = 0;
    {
        int acc0 = 0;
        for (int bb = 0; bb < 16; ++bb) {
            int c  = gh[bb];
            int ng = (c + 31) >> 5;
            if (u < acc0 + ng) { b = bb; grp = u - acc0; cnt = c; break; }
            acc0 += ng;
        }
    }
    if (b < 0) return;                 // beyond total real groups
    const int L = 16 - b;              // uniform sequence length of this group

    // A fragments: W_hh persistent in registers (4 g-tiles x 8 kc x 4 VGPR)
    bf16x8 afr[4][8];
#pragma unroll
    for (int g = 0; g < 4; ++g)
#pragma unroll
        for (int kc = 0; kc < 8; ++kc)
            afr[g][kc] = *(const bf16x8*)(WA + (((wv * 4 + g) * 8 + kc) * 64 + lane) * 8);

    if (tid < WGSEQ) {
        int slot = grp * WGSEQ + tid;
        sid_s[tid] = perm[b * BINCAP + (slot < cnt ? slot : 0)];
    }
    for (int i = tid; i < WGSEQ * HSTRIDE; i += 256) ((int*)hbuf)[i] = 0;  // both bufs
    __syncthreads();
    for (int i = tid; i < WGSEQ * SEQL; i += 256)
        words_s[(i >> 4) * 17 + (i & 15)] = word_ids[sid_s[i >> 4] * SEQL + (i & 15)];
    __syncthreads();

    f32x4 cq[4] = {{0,0,0,0},{0,0,0,0},{0,0,0,0},{0,0,0,0}};
    const char* P2c  = (const char*)P2T;
    const int pboff  = wv * 128 + hl * 16;      // byte offset within a P row
    const int rdo    = lane31 * HSTRIDE;        // ushort offset of own seq row
    const int jbase  = wv * 32 + 4 * hl;        // first j of q-group 0

    // prefetch step 0's P rows (x@W_ih^T + biases)
    f32x4 pf[4][4];
    {
        const char* pb = P2c + ((size_t)words_s[lane31 * 17] << 11) + pboff;
#pragma unroll
        for (int g = 0; g < 4; ++g)
#pragma unroll
            for (int q = 0; q < 4; ++q)
                pf[g][q] = *(const f32x4*)(pb + g * 512 + q * 32);
    }

#pragma unroll 1
    for (int t = 0; t < L; ++t) {
        const unsigned short* __restrict__ hr = hbuf[t & 1];
        unsigned short*       __restrict__ hw = hbuf[(t + 1) & 1];

        // consume prefetched P into C operands
        AccU acc[4];
#pragma unroll
        for (int g = 0; g < 4; ++g)
#pragma unroll
            for (int q = 0; q < 4; ++q)
                acc[g].q[q] = pf[g][q];

        // issue next step's P loads now; they retire under MFMA+trans below
        if (t + 1 < L) {
            const char* pb = P2c + ((size_t)words_s[lane31 * 17 + t + 1] << 11) + pboff;
#pragma unroll
            for (int g = 0; g < 4; ++g)
#pragma unroll
                for (int q = 0; q < 4; ++q)
                    pf[g][q] = *(const f32x4*)(pb + g * 512 + q * 32);
        }

        // B fragments: own seq's h^T from read buffer
        bf16x8 bf[8];
#pragma unroll
        for (int kc = 0; kc < 8; ++kc)
            bf[kc] = *(const bf16x8*)(hr + rdo + kc * 16 + hl * 8);

#pragma unroll
        for (int kc = 0; kc < 8; ++kc) {
            const bf16x8 bb = bf[kc];
#pragma unroll
            for (int g = 0; g < 4; ++g)
                acc[g].v = __builtin_amdgcn_mfma_f32_32x32x16_bf16(afr[g][kc], bb, acc[g].v, 0, 0, 0);
        }

        // cell update: no masking (uniform length), packed b64 h-writes
#pragma unroll
        for (int q = 0; q < 4; ++q) {
            HPack hp;
#pragma unroll
            for (int d = 0; d < 4; ++d) {
                const int r = q * 4 + d;
                float ig = sigm(acc[0].f[r]);
                float fg = sigm(acc[1].f[r]);
                float gg = tanhx(acc[2].f[r]);
                float og = sigm(acc[3].f[r]);
                float cn = fg * cq[q][d] + ig * gg;
                cq[q][d] = cn;
                hp.s[d] = f2bf(og * tanhx(cn));
            }
            *(unsigned long long*)(hw + rdo + jbase + 8 * q) = hp.u64;
        }
        __syncthreads();
    }

    // final cell state -> original seq order (dwordx4 stores)
    if (grp * WGSEQ + lane31 < cnt) {
        const int sid = sid_s[lane31];
#pragma unroll
        for (int q = 0; q < 4; ++q)
            *(f32x4*)(c_out + sid * HDIM + jbase + 8 * q) = cq[q];
    }
}

// ---------------------------------------------------------------------------
// Per-batch epilogue: gram -> cosine -> conv1 -> conv2 -> scorer -> sigmoid.
// ---------------------------------------------------------------------------
__global__ __launch_bounds__(256) void epilogue(
    const float* __restrict__ c_ws,
    const float* __restrict__ conv1_w, const float* __restrict__ conv1_b,
    const float* __restrict__ conv2_w, const float* __restrict__ conv2_b,
    const float* __restrict__ scorer_w, const float* __restrict__ scorer_b,
    float* __restrict__ out)
{
    __shared__ __align__(16) float reps[8 * NWRD * HDIM];   // 16KB
    __shared__ float gram_s[8 * 16];

    const int tid = threadIdx.x;
    const int b0  = blockIdx.x * 8;

    for (int i = tid; i < 8 * NWRD * HDIM; i += 256)
        reps[i] = c_ws[b0 * NWRD * HDIM + i];
    __syncthreads();

    const int bt  = tid >> 5;   // 0..7
    const int sub = tid & 31;

    float dval = 0.f;
    if (sub < 16) {
        int i = sub >> 2, j = sub & 3;
        const f32x4* ci = (const f32x4*)(reps + (bt * 4 + i) * HDIM);
        const f32x4* cj = (const f32x4*)(reps + (bt * 4 + j) * HDIM);
        f32x4 s4 = {0.f, 0.f, 0.f, 0.f};
        for (int k = 0; k < HDIM / 4; ++k) s4 += ci[k] * cj[k];
        dval = s4.x + s4.y + s4.z + s4.w;
        gram_s[bt * 16 + sub] = dval;
    }
    __syncthreads();
    float cosv = 0.f;
    if (sub < 16) {
        int i = sub >> 2, j = sub & 3;
        float di = gram_s[bt * 16 + i * 4 + i];
        float dj = gram_s[bt * 16 + j * 4 + j];
        cosv = __fdividef(dval, sqrtf(di * dj));
    }
    __syncthreads();
    if (sub < 16) gram_s[bt * 16 + sub] = cosv;
    __syncthreads();

    if (sub == 0) {
        float img[4][4];
#pragma unroll
        for (int i = 0; i < 4; ++i)
#pragma unroll
            for (int j = 0; j < 4; ++j) img[i][j] = gram_s[bt * 16 + i * 4 + j];

        float o1[4][3][3];
#pragma unroll
        for (int ch = 0; ch < 4; ++ch) {
            float w00 = conv1_w[ch*4+0], w01 = conv1_w[ch*4+1];
            float w10 = conv1_w[ch*4+2], w11 = conv1_w[ch*4+3];
            float bb  = conv1_b[ch];
#pragma unroll
            for (int y = 0; y < 3; ++y)
#pragma unroll
                for (int x = 0; x < 3; ++x) {
                    float s = bb + w00*img[y][x]   + w01*img[y][x+1]
                                 + w10*img[y+1][x] + w11*img[y+1][x+1];
                    o1[ch][y][x] = s > 0.f ? s : 0.f;
                }
        }
        float sc = scorer_b[0];
#pragma unroll
        for (int oc = 0; oc < 8; ++oc) {
            float bb = conv2_b[oc];
#pragma unroll
            for (int y = 0; y < 2; ++y)
#pragma unroll
                for (int x = 0; x < 2; ++x) {
                    float s = bb;
#pragma unroll
                    for (int ic = 0; ic < 4; ++ic) {
                        const float* w = conv2_w + oc * 16 + ic * 4;
                        s += w[0]*o1[ic][y][x]   + w[1]*o1[ic][y][x+1]
                           + w[2]*o1[ic][y+1][x] + w[3]*o1[ic][y+1][x+1];
                    }
                    float rl = s > 0.f ? s : 0.f;
                    sc += rl * scorer_w[oc * 4 + y * 2 + x];
                }
        }
        out[blockIdx.x * 8 + bt] = sigm(sc);
    }
}

extern "C" void kernel_launch(void* const* d_in, const int* in_sizes, int n_in,
                              void* d_out, int out_size, void* d_ws, size_t ws_size,
                              hipStream_t stream)
{
    const int*   word_ids = (const int*)d_in[0];
    const int*   lengths  = (const int*)d_in[1];
    const float* emb      = (const float*)d_in[2];
    const float* W_ih     = (const float*)d_in[3];
    const float* W_hh     = (const float*)d_in[4];
    const float* b_ih     = (const float*)d_in[5];
    const float* b_hh     = (const float*)d_in[6];
    const float* conv1_w  = (const float*)d_in[7];
    const float* conv1_b  = (const float*)d_in[8];
    const float* conv2_w  = (const float*)d_in[9];
    const float* conv2_b  = (const float*)d_in[10];
    const float* scorer_w = (const float*)d_in[11];
    const float* scorer_b = (const float*)d_in[12];
    float* out = (float*)d_out;

    // workspace layout
    char* ws = (char*)d_ws;
    float*          P2T  = (float*)(ws + 0);                  // 128 KB
    unsigned short* WA   = (unsigned short*)(ws + (128<<10)); // 128 KB
    int*            perm = (int*)(ws + (256<<10));            // 160 KB
    int*            gh   = (int*)(ws + (424<<10));            // 64 B bin counters
    float*          c_ws = (float*)(ws + (512<<10));          // 16 MB

    hipMemsetAsync(gh, 0, 16 * sizeof(int), stream);
    prep4   <<<512,    256, 0, stream>>>(emb, W_ih, b_ih, b_hh, W_hh, lengths,
                                         P2T, WA, perm, gh);
    lstm5   <<<NUNITS, 256, 0, stream>>>(word_ids, perm, gh, P2T, WA, c_ws);
    epilogue<<<BSZ / 8, 256, 0, stream>>>(c_ws, conv1_w, conv1_b, conv2_w, conv2_b,
                                          scorer_w, scorer_b, out);
}